// Round 10
// baseline (816.048 us; speedup 1.0000x reference)
//
#include <hip/hip_runtime.h>
#include <float.h>
#include <math.h>

// Problem: z (32,256,32,32) f32, W (8192,256) f32.
// Outputs flat: z_q [0,8388608) | loss [8388608] | index [8388609,8421377) | perp [8421377]
#define OUT_LOSS 8388608
#define OUT_IDX  8388609
#define OUT_PERP 8421377

// Workspace layout (bytes)  (~45.1 MB total)
// Fragment-linear blocked layouts (ushort offsets):
//   X[kc][row>>4][q][row&15][8e] with kc=k>>5, q=(k>>3)&3, e=k&7.
// Each 16-row x 32-k "group" is a contiguous 1KB block; lane l's 16B slot
// (l*16) is exactly its mfma_16x16x32 fragment (col=l&15, q=l>>4).
// NOTE: WS_ZT (f32 zT[32768][256], 32MB) ALIASES WS_ZH+WS_ZL — Zh/Zl are dead
// after k_main; k_zt writes zT after k_main, consumed by k_cand/k_full.
#define WS_ZH    0ull          // ushort[8][2048][512]  bf16 hi of z
#define WS_ZL    16777216ull   // ushort[8][2048][512]  bf16 lo of z
#define WS_ZT    0ull          // float[32768][256]     (aliases Zh+Zl)
#define WS_WH    33554432ull   // ushort[8][512][512]   bf16 hi of W
#define WS_S     37748736ull   // float[32768]  ||z||^2 np-pairwise
#define WS_B     37879808ull   // float[8192]   ||W||^2 np-pairwise
#define WS_MAXW  37912576ull   // uint           max_j B_j (bits)
#define WS_IDX   37912640ull   // int[32768]
#define WS_HIST  38043712ull   // int[8192]
#define WS_CAND  38076480ull   // int[3*32768]
#define WS_FULL  38469696ull   // int[32768]
#define WS_FKEY  38600768ull   // u64[32768]
#define WS_CNT   38862912ull   // int[2]
#define WS_LOSS  38862920ull   // double
#define WS_WL    38866944ull   // ushort[8][512][512]   bf16 lo of W (8MB)

typedef short v8s __attribute__((ext_vector_type(8)));
typedef float v4f __attribute__((ext_vector_type(4)));

__device__ __forceinline__ unsigned short bf16rne(float f) {
  unsigned u = __float_as_uint(f);
  return (unsigned short)((u + 0x7FFFu + ((u >> 16) & 1u)) >> 16);
}
__device__ __forceinline__ float bf16tof(unsigned short h) {
  return __uint_as_float(((unsigned)h) << 16);
}

// async global->LDS DMA, 16B/lane. LDS dest is wave-uniform base; HW writes
// lane l's 16B at base + l*16. Global src is per-lane (we pass base + lane*16).
__device__ __forceinline__ void gl_lds16(const void* g, void* l) {
  __builtin_amdgcn_global_load_lds(
      (const __attribute__((address_space(1))) unsigned int*)g,
      (__attribute__((address_space(3))) unsigned int*)l, 16, 0, 0);
}

__global__ void k_zero(int* __restrict__ hist, unsigned long long* __restrict__ fkey,
                       int* __restrict__ cnt, double* __restrict__ loss,
                       unsigned* __restrict__ maxw) {
  const int i = blockIdx.x * 256 + threadIdx.x;   // grid 161
  if (i < 8192) hist[i] = 0;
  else if (i < 40960) fkey[i - 8192] = ~0ull;
  else if (i == 40960) cnt[0] = 0;
  else if (i == 40961) cnt[1] = 0;
  else if (i == 40962) *loss = 0.0;
  else if (i == 40963) *maxw = 0u;
}

// W -> bf16 hi + lo planes, fragment-linear layout.
// ushort off(j,k) = (k>>5)*262144 + (j>>4)*512 + ((k>>3)&3)*128 + (j&15)*8 + (k&7)
__global__ __launch_bounds__(256) void k_split(const float* __restrict__ W,
                                               unsigned short* __restrict__ Wh,
                                               unsigned short* __restrict__ Wl) {
  const int u = blockIdx.x * 256 + threadIdx.x;   // grid 1024
  const int kc = u >> 15, grp = (u >> 6) & 511, q = (u >> 4) & 3, col = u & 15;
  const int j = grp * 16 + col, k0 = kc * 32 + q * 8;
  const float4 w0 = *(const float4*)(W + (size_t)j * 256 + k0);
  const float4 w1 = *(const float4*)(W + (size_t)j * 256 + k0 + 4);
  const float wv[8] = {w0.x, w0.y, w0.z, w0.w, w1.x, w1.y, w1.z, w1.w};
  unsigned short h[8] __attribute__((aligned(16)));
  unsigned short l[8] __attribute__((aligned(16)));
#pragma unroll
  for (int i = 0; i < 8; ++i) {
    h[i] = bf16rne(wv[i]);
    l[i] = bf16rne(__fsub_rn(wv[i], bf16tof(h[i])));
  }
  *(uint4*)(Wh + (size_t)u * 8) = *(const uint4*)h;
  *(uint4*)(Wl + (size_t)u * 8) = *(const uint4*)l;
}

// z (32,256,32,32) -> Zh/Zl fragment-linear bf16 (n = b*1024 + p).
__global__ __launch_bounds__(256) void k_splitz(const float* __restrict__ z,
    unsigned short* __restrict__ Zh, unsigned short* __restrict__ Zl) {
  const int gt = blockIdx.x * 256 + threadIdx.x;   // grid 1024
  const int kc = gt >> 15;
  const int n  = gt & 32767;
  const int b = n >> 10, p = n & 1023;
  const float* zp = z + (size_t)b * 262144 + (size_t)(kc * 32) * 1024 + p;
  unsigned short hh[32] __attribute__((aligned(16)));
  unsigned short ll[32] __attribute__((aligned(16)));
#pragma unroll
  for (int i = 0; i < 32; ++i) {
    const float v = zp[(size_t)i * 1024];
    const unsigned short h = bf16rne(v);
    hh[i] = h;
    ll[i] = bf16rne(__fsub_rn(v, bf16tof(h)));
  }
  const size_t o = (size_t)kc * 1048576 + (size_t)(n >> 4) * 512 + (size_t)(n & 15) * 8;
#pragma unroll
  for (int q = 0; q < 4; ++q) *(uint4*)(Zh + o + q * 128) = *(const uint4*)(hh + q * 8);
#pragma unroll
  for (int q = 0; q < 4; ++q) *(uint4*)(Zl + o + q * 128) = *(const uint4*)(ll + q * 8);
}

// z -> zT[n][c] f32 (row-major per pixel). Runs AFTER k_main (aliases Zh/Zl).
__global__ __launch_bounds__(256) void k_zt(const float* __restrict__ z,
                                            float* __restrict__ zT) {
  const int gt = blockIdx.x * 256 + threadIdx.x;   // grid 1024
  const int kc = gt >> 15;
  const int n  = gt & 32767;
  const int b = n >> 10, p = n & 1023;
  const float* zp = z + (size_t)b * 262144 + (size_t)(kc * 32) * 1024 + p;
  float v[32] __attribute__((aligned(16)));
#pragma unroll
  for (int i = 0; i < 32; ++i) v[i] = zp[(size_t)i * 1024];
  float* dst = zT + (size_t)n * 256 + kc * 32;
#pragma unroll
  for (int j = 0; j < 8; ++j) *(float4*)(dst + j * 4) = *(const float4*)(v + j * 4);
}

// numpy pairwise sum of squares, n=256 (two 128-blocks, 8 accumulators)
__device__ __forceinline__ float np_sumsq256(const float* __restrict__ base,
                                             const int stride) {
  float h[2];
#pragma unroll
  for (int half = 0; half < 2; ++half) {
    const float* a = base + (size_t)(half * 128) * stride;
    float r[8];
#pragma unroll
    for (int k = 0; k < 8; ++k) { const float v = a[(size_t)k * stride]; r[k] = __fmul_rn(v, v); }
    for (int i = 8; i < 128; i += 8) {
#pragma unroll
      for (int k = 0; k < 8; ++k) {
        const float v = a[(size_t)(i + k) * stride];
        r[k] = __fadd_rn(r[k], __fmul_rn(v, v));
      }
    }
    h[half] = __fadd_rn(
        __fadd_rn(__fadd_rn(r[0], r[1]), __fadd_rn(r[2], r[3])),
        __fadd_rn(__fadd_rn(r[4], r[5]), __fadd_rn(r[6], r[7])));
  }
  return __fadd_rn(h[0], h[1]);
}

__global__ __launch_bounds__(256) void k_sz(const float* __restrict__ z,
                                            float* __restrict__ S) {
  const int n = blockIdx.x * 256 + threadIdx.x;   // grid 128
  S[n] = np_sumsq256(z + (size_t)(n >> 10) * 262144 + (n & 1023), 1024);
}

__global__ __launch_bounds__(256) void k_wsq(const float* __restrict__ W,
                                             float* __restrict__ B,
                                             unsigned* __restrict__ maxw) {
  const int j = blockIdx.x * 256 + threadIdx.x;   // grid 32
  const float b = np_sumsq256(W + (size_t)j * 256, 1);
  B[j] = b;
  atomicMax(maxw, __float_as_uint(b));
}

// stable merge of two sorted-3 lists (values + indices for top-2)
__device__ __forceinline__ void merge5(float& a1, int& ai1, float& a2, int& ai2,
                                       float& a3, float b1, int bi1, float b2,
                                       int bi2, float b3) {
  const bool t1 = (b1 < a1) || (b1 == a1 && bi1 < ai1);
  const float w2v = t1 ? b2 : a2; const int w2i = t1 ? bi2 : ai2;
  const float w3v = t1 ? b3 : a3;
  const float l1v = t1 ? a1 : b1; const int l1i = t1 ? ai1 : bi1;
  const float l2v = t1 ? a2 : b2;
  const float n1v = t1 ? b1 : a1; const int n1i = t1 ? bi1 : ai1;
  const bool t2 = (w2v < l1v) || (w2v == l1v && w2i < l1i);
  a1 = n1v; ai1 = n1i;
  a2 = t2 ? w2v : l1v; ai2 = t2 ? w2i : l1i;
  a3 = t2 ? fminf(w3v, l1v) : fminf(w2v, l2v);
}

// Coarse pass v10: C~ = zh*wh + zl*wh + zh*wl (3 MFMAs, per-acc chain order
// identical to v4-v9 -> bit-identical numerics); window is 2-ulp dominated.
// BARRIER-FREE loop at the proven no-spill occupancy: 256-thread blocks,
// 2 blocks/CU = 8 waves/CU (256-unified-reg budget; round 8's identical
// structure spilled ONLY because 512x2 = 16 waves/CU caps at 128 regs).
// A hi+lo in LDS (read-only after prologue, 64 KiB -> 2 blocks/CU); BOTH
// B planes stream global->registers, double-buffered A/B a FULL iteration
// ahead (fragments issued ~150+ cyc + 8-wave TLP before use -> L2 latency
// hidden). Zero barriers across the 512-iteration loop; waves free-run.
// Manual 2-phase unroll keeps all fragment indexing compile-time static.
#define AH_OFF   0        // 32 KB  A hi: [kc][4 groups][1KB]
#define AL_OFF   32768    // 32 KB  A lo
#define SC_OFF   0        // merge scratch (reuses AH after loop + barrier)
#define SMEM_SZ  65536
__global__ __launch_bounds__(256, 2) void k_main(
    const unsigned short* __restrict__ Zh, const unsigned short* __restrict__ Zl,
    const unsigned short* __restrict__ Wh, const unsigned short* __restrict__ Wl,
    const float* __restrict__ S, const float* __restrict__ B,
    const unsigned* __restrict__ maxw, int* __restrict__ idxb,
    int* __restrict__ cand, int* __restrict__ full, int* __restrict__ cnt) {
  extern __shared__ __align__(16) char smem[];
  const int t = threadIdx.x;
  const int w = t >> 6, lane = t & 63, col = lane & 15, q = lane >> 4;
  const int phalf = w >> 1, strip = w & 1;
  const int n0 = blockIdx.x << 6;             // grid 512

  float spx[8];
#pragma unroll
  for (int s = 0; s < 8; ++s)
    spx[s] = S[n0 + phalf * 32 + (s >> 2) * 16 + q * 4 + (s & 3)];

  // ---- stage A via DMA (once): wave w stages kc = 2w, 2w+1 (hi + lo) ----
  {
#pragma unroll
    for (int c = 0; c < 2; ++c) {
      const int kc = w * 2 + c;
      const size_t ab = (size_t)kc * 1048576 + (size_t)(n0 >> 4) * 512 + (size_t)lane * 8;
#pragma unroll
      for (int g = 0; g < 4; ++g) {
        gl_lds16(Zh + ab + (size_t)g * 512, smem + AH_OFF + kc * 4096 + g * 1024);
        gl_lds16(Zl + ab + (size_t)g * 512, smem + AL_OFF + kc * 4096 + g * 1024);
      }
    }
  }
  // ---- B fragment stream: per-wave strip base; fragment f = it*4 + nt,
  //      byte-offset add off(f) = ((f>>2)&7)*512KB_k + (f>>5)*8KB_ct + (f&3)*1KB
  const unsigned short* pWh = Wh + (size_t)(strip * 4) * 512 + (size_t)lane * 8;
  const unsigned short* pWl = Wl + (size_t)(strip * 4) * 512 + (size_t)lane * 8;
#define BOFF(f) ((size_t)(((f) >> 2) & 7) * 262144 + (size_t)((f) >> 5) * 4096 \
                 + (size_t)((f) & 3) * 512)
  v8s bhA[4], blA[4], bhB[4], blB[4];
#pragma unroll
  for (int nt = 0; nt < 4; ++nt) {            // prologue: it=0 -> buf A
    bhA[nt] = *(const v8s*)(pWh + BOFF(nt));
    blA[nt] = *(const v8s*)(pWl + BOFF(nt));
  }
  __syncthreads();   // drains vmcnt -> A-LDS visible; last barrier before loop

  float m1[8], m2[8], m3[8]; int i1[8], i2[8];
#pragma unroll
  for (int s = 0; s < 8; ++s) {
    m1[s] = FLT_MAX; m2[s] = FLT_MAX; m3[s] = FLT_MAX;
    i1[s] = 0x7fffffff; i2[s] = 0x7fffffff;
  }

  v4f acc[2][4];
#pragma unroll
  for (int pt = 0; pt < 2; ++pt)
#pragma unroll
    for (int nt = 0; nt < 4; ++nt) acc[pt][nt] = (v4f){0.f, 0.f, 0.f, 0.f};

  for (int it2 = 0; it2 < 256; ++it2) {       // 512 its, 2 per pass, NO barriers
    // ===== phase A: it = 2*it2 (kc even, never an epilogue) =====
    {
      const int it = it2 * 2;
      const int kc = it & 7;
      const int fn = ((it + 1) * 4) & 2047;   // next it -> buf B
#pragma unroll
      for (int nt = 0; nt < 4; ++nt) {
        bhB[nt] = *(const v8s*)(pWh + BOFF(fn + nt));
        blB[nt] = *(const v8s*)(pWl + BOFF(fn + nt));
      }
      v8s ah[2], al[2];
#pragma unroll
      for (int pt = 0; pt < 2; ++pt) {
        const int g = phalf * 2 + pt;
        ah[pt] = *(const v8s*)(smem + AH_OFF + kc * 4096 + g * 1024 + lane * 16);
        al[pt] = *(const v8s*)(smem + AL_OFF + kc * 4096 + g * 1024 + lane * 16);
      }
#pragma unroll
      for (int nt = 0; nt < 4; ++nt) {
#pragma unroll
        for (int pt = 0; pt < 2; ++pt) {
          acc[pt][nt] = __builtin_amdgcn_mfma_f32_16x16x32_bf16(ah[pt], bhA[nt], acc[pt][nt], 0, 0, 0);
          acc[pt][nt] = __builtin_amdgcn_mfma_f32_16x16x32_bf16(al[pt], bhA[nt], acc[pt][nt], 0, 0, 0);
          acc[pt][nt] = __builtin_amdgcn_mfma_f32_16x16x32_bf16(ah[pt], blA[nt], acc[pt][nt], 0, 0, 0);
        }
      }
    }
    // ===== phase B: it = 2*it2+1 (kc odd; epilogue when kc==7) =====
    {
      const int it = it2 * 2 + 1;
      const int kc = it & 7;
      const int fn = ((it + 1) * 4) & 2047;   // next it -> buf A
#pragma unroll
      for (int nt = 0; nt < 4; ++nt) {
        bhA[nt] = *(const v8s*)(pWh + BOFF(fn + nt));
        blA[nt] = *(const v8s*)(pWl + BOFF(fn + nt));
      }
      v8s ah[2], al[2];
#pragma unroll
      for (int pt = 0; pt < 2; ++pt) {
        const int g = phalf * 2 + pt;
        ah[pt] = *(const v8s*)(smem + AH_OFF + kc * 4096 + g * 1024 + lane * 16);
        al[pt] = *(const v8s*)(smem + AL_OFF + kc * 4096 + g * 1024 + lane * 16);
      }
#pragma unroll
      for (int nt = 0; nt < 4; ++nt) {
#pragma unroll
        for (int pt = 0; pt < 2; ++pt) {
          acc[pt][nt] = __builtin_amdgcn_mfma_f32_16x16x32_bf16(ah[pt], bhB[nt], acc[pt][nt], 0, 0, 0);
          acc[pt][nt] = __builtin_amdgcn_mfma_f32_16x16x32_bf16(al[pt], bhB[nt], acc[pt][nt], 0, 0, 0);
          acc[pt][nt] = __builtin_amdgcn_mfma_f32_16x16x32_bf16(ah[pt], blB[nt], acc[pt][nt], 0, 0, 0);
        }
      }
      if (kc == 7) {                           // epilogue for this 128-code tile
        const int ct = it >> 3;
#pragma unroll
        for (int nt = 0; nt < 4; ++nt) {
          const int code = ct * 128 + strip * 64 + nt * 16 + col;
          const float bb = B[code];
#pragma unroll
          for (int pt = 0; pt < 2; ++pt) {
            const v4f a = acc[pt][nt];
#pragma unroll
            for (int r = 0; r < 4; ++r) {
              const int s = pt * 4 + r;
              const float d = __fsub_rn(__fadd_rn(spx[s], bb), __fmul_rn(2.f, a[r]));
              const bool c1 = (d < m1[s]);
              const bool c2 = (d < m2[s]);
              const bool c3 = (d < m3[s]);
              m3[s] = c2 ? m2[s] : (c3 ? d : m3[s]);
              m2[s] = c1 ? m1[s] : (c2 ? d : m2[s]);
              i2[s] = c1 ? i1[s] : (c2 ? code : i2[s]);
              m1[s] = c1 ? d : m1[s];
              i1[s] = c1 ? code : i1[s];
            }
          }
#pragma unroll
          for (int pt = 0; pt < 2; ++pt) acc[pt][nt] = (v4f){0.f, 0.f, 0.f, 0.f};
        }
      }
    }
  }
#undef BOFF

  // in-wave merge across the 16 col-lanes
#pragma unroll
  for (int s = 0; s < 8; ++s) {
    for (int msk = 1; msk < 16; msk <<= 1) {
      const float b1 = __shfl_xor(m1[s], msk, 16);
      const int  bi1 = __shfl_xor(i1[s], msk, 16);
      const float b2 = __shfl_xor(m2[s], msk, 16);
      const int  bi2 = __shfl_xor(i2[s], msk, 16);
      const float b3 = __shfl_xor(m3[s], msk, 16);
      merge5(m1[s], i1[s], m2[s], i2[s], m3[s], b1, bi1, b2, bi2, b3);
    }
  }
  __syncthreads();   // all waves done with LDS A -> safe to reuse as scratch
  float* sc = (float*)(smem + SC_OFF);        // [px][strip][5]
  if (col == 0) {
#pragma unroll
    for (int s = 0; s < 8; ++s) {
      const int px = phalf * 32 + (s >> 2) * 16 + q * 4 + (s & 3);
      const int base = (px * 2 + strip) * 5;
      sc[base]     = m1[s];
      sc[base + 1] = __int_as_float(i1[s]);
      sc[base + 2] = m2[s];
      sc[base + 3] = __int_as_float(i2[s]);
      sc[base + 4] = m3[s];
    }
  }
  __syncthreads();
  if (t < 64) {
    const int base0 = t * 10;
    float A1 = sc[base0], A2 = sc[base0 + 2], A3 = sc[base0 + 4];
    int AI1 = __float_as_int(sc[base0 + 1]), AI2 = __float_as_int(sc[base0 + 3]);
    {
      const int base = base0 + 5;
      merge5(A1, AI1, A2, AI2, A3, sc[base], __float_as_int(sc[base + 1]),
             sc[base + 2], __float_as_int(sc[base + 3]), sc[base + 4]);
    }
    const int n = n0 + t;
    idxb[n] = AI1;
    // window: 2*(2^-16*||z||*max||w|| + slack) + 2 ulp(m1)
    const float nw = sqrtf(S[n]) * sqrtf(__uint_as_float(*maxw));
    const float win = 2.0f * (1.52587890625e-05f * nw + 1e-6f)
                    + 2.0f * ldexpf(1.0f, ilogbf(fmaxf(A1, 1e-30f)) - 23);
    if (A2 <= A1 + win) {
      if (A3 <= A1 + win) {
        const int p = atomicAdd(&cnt[1], 1);
        full[p] = n;
      } else {
        const int p = atomicAdd(&cnt[0], 1);
        cand[3 * p] = n; cand[3 * p + 1] = AI1; cand[3 * p + 2] = AI2;
      }
    }
  }
}

// exact np-chain re-eval of the two candidates (z rows via zT, sequential)
__global__ __launch_bounds__(256) void k_cand(const float* __restrict__ zT,
    const float* __restrict__ W, const float* __restrict__ S,
    const float* __restrict__ B, const int* __restrict__ cand,
    const int* __restrict__ cnt, int* __restrict__ idxb) {
  const int e = blockIdx.x * 256 + threadIdx.x;   // grid 128
  if (e >= cnt[0]) return;
  const int n = cand[3 * e], ca = cand[3 * e + 1], cb = cand[3 * e + 2];
  const float* zp = zT + (size_t)n * 256;
  const float* wa = W + (size_t)ca * 256;
  const float* wb = W + (size_t)cb * 256;
  float a1 = 0.f, a2 = 0.f;
  for (int c = 0; c < 256; ++c) {
    const float zv = zp[c];
    a1 = __builtin_fmaf(zv, wa[c], a1);
    a2 = __builtin_fmaf(zv, wb[c], a2);
  }
  const float d1 = __fsub_rn(__fadd_rn(S[n], B[ca]), __fmul_rn(2.f, a1));
  const float d2 = __fsub_rn(__fadd_rn(S[n], B[cb]), __fmul_rn(2.f, a2));
  idxb[n] = (d1 < d2) ? ca : ((d2 < d1) ? cb : min(ca, cb));
}

// Exact full argmin. Unit = (32-px group, 256-code tile) -> units = nG*32.
__global__ __launch_bounds__(256) void k_full(const float* __restrict__ zT,
    const float* __restrict__ W, const float* __restrict__ S,
    const float* __restrict__ B, const int* __restrict__ full,
    const int* __restrict__ cnt, unsigned long long* __restrict__ fkey) {
  extern __shared__ __align__(16) char fsm[];
  float* zsf = (float*)fsm;                    // [256][32] (swizzled quads)
  float* wt  = (float*)(fsm + 32768);          // [32][257]
  float* mv  = (float*)(fsm + 32768 + 32896);  // [32][33]
  int*   mi  = (int*)(fsm + 32768 + 32896 + 4224);
  const int t = threadIdx.x;
  const int pg = t & 7, cg = t >> 3;
  const int fN = min(cnt[1], 32768);
  const int units = ((fN + 31) >> 5) << 5;
  for (int e = blockIdx.x; e < units; e += 2048) {
    const int g = e >> 5, tt = e & 31;
    const int c0 = tt << 8;
    __syncthreads();                           // LDS reuse guard
    {                                          // stage z from zT (coalesced)
      const int px = t >> 3, c8 = t & 7;
      const int f = (g << 5) + px;
      const int n = (f < fN) ? full[f] : full[0];
      const float4* src = (const float4*)(zT + (size_t)n * 256 + c8 * 32);
      const int colq = (((px >> 2) ^ c8) << 2) + (px & 3);
#pragma unroll
      for (int j = 0; j < 8; ++j) {
        const float4 v = src[j];
        const int c = c8 * 32 + j * 4;
        zsf[(c    ) * 32 + colq] = v.x;
        zsf[(c + 1) * 32 + colq] = v.y;
        zsf[(c + 2) * 32 + colq] = v.z;
        zsf[(c + 3) * 32 + colq] = v.w;
      }
    }
    float s4[4];
#pragma unroll
    for (int i = 0; i < 4; ++i) {
      const int f = (g << 5) + (pg << 2) + i;
      s4[i] = (f < fN) ? S[full[f]] : 0.f;
    }
    float bm[4]; int bj[4];
#pragma unroll
    for (int i = 0; i < 4; ++i) { bm[i] = FLT_MAX; bj[i] = 0x7fffffff; }
    float acc[4][8];
#pragma unroll
    for (int i = 0; i < 4; ++i)
#pragma unroll
      for (int u = 0; u < 8; ++u) acc[i][u] = 0.f;
    for (int kc = 0; kc < 8; ++kc) {
      const int kb = kc << 5;
      __syncthreads();
#pragma unroll
      for (int p = 0; p < 8; ++p) {          // W chunk, transposed store
        const int jl = (t >> 3) + (p << 5);
        const float4 wv4 =
            *(const float4*)&W[(size_t)(c0 + jl) * 256 + kb + ((t & 7) << 2)];
        const int k0 = (t & 7) << 2;
        wt[(k0    ) * 257 + jl] = wv4.x;
        wt[(k0 + 1) * 257 + jl] = wv4.y;
        wt[(k0 + 2) * 257 + jl] = wv4.z;
        wt[(k0 + 3) * 257 + jl] = wv4.w;
      }
      __syncthreads();
      const int zq = ((pg ^ kc) & 7) << 2;
      for (int k = 0; k < 32; ++k) {
        const float4 z4 = *(const float4*)&zsf[(kb + k) * 32 + zq];
        const float4 wA = *(const float4*)&wt[k * 257 + (cg << 3)];
        const float4 wB = *(const float4*)&wt[k * 257 + (cg << 3) + 4];
        const float zv[4] = {z4.x, z4.y, z4.z, z4.w};
        const float wv[8] = {wA.x, wA.y, wA.z, wA.w, wB.x, wB.y, wB.z, wB.w};
#pragma unroll
        for (int i = 0; i < 4; ++i)
#pragma unroll
          for (int u = 0; u < 8; ++u)
            acc[i][u] = __builtin_fmaf(zv[i], wv[u], acc[i][u]);
      }
    }
#pragma unroll
    for (int u = 0; u < 8; ++u) {              // tile epilogue
      const int code = c0 + (cg << 3) + u;
      const float bb = B[code];
#pragma unroll
      for (int i = 0; i < 4; ++i) {
        const float d = __fsub_rn(__fadd_rn(s4[i], bb), __fmul_rn(2.f, acc[i][u]));
        if (d < bm[i]) { bm[i] = d; bj[i] = code; }
      }
    }
    __syncthreads();                           // merge across cg
#pragma unroll
    for (int i = 0; i < 4; ++i) {
      const int px = (pg << 2) + i;
      mv[px * 33 + cg] = bm[i];
      mi[px * 33 + cg] = bj[i];
    }
    __syncthreads();
    if (t < 32) {
      float m = mv[t * 33]; int j = mi[t * 33];
      for (int c = 1; c < 32; ++c) {
        const float v = mv[t * 33 + c]; const int vi = mi[t * 33 + c];
        if (v < m || (v == m && vi < j)) { m = v; j = vi; }
      }
      const int f = (g << 5) + t;
      if (f < fN) {
        const unsigned long long key =
            (((unsigned long long)__float_as_uint(m)) << 13) | (unsigned)j;
        atomicMin(&fkey[f], key);
      }
    }
  }
}

__global__ __launch_bounds__(256) void k_fullfin(const int* __restrict__ full,
    const int* __restrict__ cnt, const unsigned long long* __restrict__ fkey,
    int* __restrict__ idxb) {
  const int f = blockIdx.x * 256 + threadIdx.x;   // grid 128
  if (f < cnt[1]) idxb[full[f]] = (int)(fkey[f] & 8191ull);
}

// z_q gather (STE rounding) + loss + histogram + index output
__global__ __launch_bounds__(256) void k_zq(const float* __restrict__ z,
    const float* __restrict__ W, const int* __restrict__ idxb,
    float* __restrict__ out, double* __restrict__ loss, int* __restrict__ hist) {
  __shared__ float red[256];
  const int t = threadIdx.x;
  const int tx = t & 63, ty = t >> 6;
  const int n0 = blockIdx.x << 6;            // grid 512
  const int n = n0 + tx;
  const int b = n >> 10;
  const int p = n & 1023;
  const int myidx = idxb[n];
  const float* wrow = W + (size_t)myidx * 256;
  float lsum = 0.f;
#pragma unroll 4
  for (int cc = 0; cc < 64; ++cc) {
    const int c = ty * 64 + cc;
    const float qv = wrow[c];
    const size_t off = (size_t)b * 262144 + (size_t)c * 1024 + p;
    const float zv = z[off];
    const float d = __fsub_rn(qv, zv);
    lsum = __builtin_fmaf(d, d, lsum);
    out[off] = __fadd_rn(zv, d);
  }
  red[t] = lsum;
  __syncthreads();
  for (int o = 128; o > 0; o >>= 1) {
    if (t < o) red[t] += red[t + o];
    __syncthreads();
  }
  if (t == 0) atomicAdd(loss, (double)red[0]);
  if (ty == 0) atomicAdd(&hist[myidx], 1);
  if (ty == 1) out[OUT_IDX + n] = (float)myidx;
}

__global__ void k_final(const int* __restrict__ hist,
                        const double* __restrict__ loss,
                        float* __restrict__ out) {
  __shared__ double sh[256];
  const int t = threadIdx.x;
  double s = 0.0;
  for (int j = t; j < 8192; j += 256) {
    const double e = (double)hist[j] / 32768.0;
    s += e * log(e + 1e-10);
  }
  sh[t] = s;
  __syncthreads();
  for (int off = 128; off > 0; off >>= 1) {
    if (t < off) sh[t] += sh[t + off];
    __syncthreads();
  }
  if (t == 0) {
    out[OUT_PERP] = (float)exp(-sh[0]);
    out[OUT_LOSS] = (float)(1.25 * (*loss) / 8388608.0);
  }
}

extern "C" void kernel_launch(void* const* d_in, const int* in_sizes, int n_in,
                              void* d_out, int out_size, void* d_ws, size_t ws_size,
                              hipStream_t stream) {
  const float* z = (const float*)d_in[0];
  const float* W = (const float*)d_in[1];
  float* out = (float*)d_out;
  char* ws = (char*)d_ws;
  unsigned short* Zh = (unsigned short*)(ws + WS_ZH);
  unsigned short* Zl = (unsigned short*)(ws + WS_ZL);
  unsigned short* Wh = (unsigned short*)(ws + WS_WH);
  unsigned short* Wl = (unsigned short*)(ws + WS_WL);
  float*  zT   = (float*)(ws + WS_ZT);   // aliases Zh+Zl (dead after k_main)
  float*  S    = (float*)(ws + WS_S);
  float*  B    = (float*)(ws + WS_B);
  unsigned* maxw = (unsigned*)(ws + WS_MAXW);
  int*    idxb = (int*)(ws + WS_IDX);
  int*    hist = (int*)(ws + WS_HIST);
  int*    cand = (int*)(ws + WS_CAND);
  int*    full = (int*)(ws + WS_FULL);
  unsigned long long* fkey = (unsigned long long*)(ws + WS_FKEY);
  int*    cnt  = (int*)(ws + WS_CNT);
  double* loss = (double*)(ws + WS_LOSS);

  hipLaunchKernelGGL(k_zero,    dim3(161),  dim3(256), 0, stream, hist, fkey, cnt, loss, maxw);
  hipLaunchKernelGGL(k_split,   dim3(1024), dim3(256), 0, stream, W, Wh, Wl);
  hipLaunchKernelGGL(k_splitz,  dim3(1024), dim3(256), 0, stream, z, Zh, Zl);
  hipLaunchKernelGGL(k_sz,      dim3(128),  dim3(256), 0, stream, z, S);
  hipLaunchKernelGGL(k_wsq,     dim3(32),   dim3(256), 0, stream, W, B, maxw);
  hipLaunchKernelGGL(k_main,    dim3(512),  dim3(256), SMEM_SZ, stream,
                     Zh, Zl, Wh, Wl, S, B, maxw, idxb, cand, full, cnt);
  hipLaunchKernelGGL(k_zt,      dim3(1024), dim3(256), 0, stream, z, zT);
  hipLaunchKernelGGL(k_cand,    dim3(128),  dim3(256), 0, stream, zT, W, S, B, cand, cnt, idxb);
  hipLaunchKernelGGL(k_full,    dim3(2048), dim3(256), 74112, stream, zT, W, S, B, full, cnt, fkey);
  hipLaunchKernelGGL(k_fullfin, dim3(128),  dim3(256), 0, stream, full, cnt, fkey, idxb);
  hipLaunchKernelGGL(k_zq,      dim3(512),  dim3(256), 0, stream, z, W, idxb, out, loss, hist);
  hipLaunchKernelGGL(k_final,   dim3(1),    dim3(256), 0, stream, hist, loss, out);
}

// Round 11
// 698.005 us; speedup vs baseline: 1.1691x; 1.1691x over previous
//
#include <hip/hip_runtime.h>
#include <float.h>
#include <math.h>

// Problem: z (32,256,32,32) f32, W (8192,256) f32.
// Outputs flat: z_q [0,8388608) | loss [8388608] | index [8388609,8421377) | perp [8421377]
#define OUT_LOSS 8388608
#define OUT_IDX  8388609
#define OUT_PERP 8421377

// Workspace layout (bytes)  (~45.1 MB total)
// Fragment-linear blocked layouts (ushort offsets):
//   X[kc][row>>4][q][row&15][8e] with kc=k>>5, q=(k>>3)&3, e=k&7.
// Each 16-row x 32-k "group" is a contiguous 1KB block; lane l's 16B slot
// (l*16) is exactly its mfma_16x16x32 fragment (col=l&15, q=l>>4).
// NOTE: WS_ZT (f32 zT[32768][256], 32MB) ALIASES WS_ZH+WS_ZL — Zh/Zl are dead
// after k_main; k_zt writes zT after k_main, consumed by k_cand/k_full.
#define WS_ZH    0ull          // ushort[8][2048][512]  bf16 hi of z
#define WS_ZL    16777216ull   // ushort[8][2048][512]  bf16 lo of z
#define WS_ZT    0ull          // float[32768][256]     (aliases Zh+Zl)
#define WS_WH    33554432ull   // ushort[8][512][512]   bf16 hi of W
#define WS_S     37748736ull   // float[32768]  ||z||^2 np-pairwise
#define WS_B     37879808ull   // float[8192]   ||W||^2 np-pairwise
#define WS_MAXW  37912576ull   // uint           max_j B_j (bits)
#define WS_IDX   37912640ull   // int[32768]
#define WS_HIST  38043712ull   // int[8192]
#define WS_CAND  38076480ull   // int[3*32768]
#define WS_FULL  38469696ull   // int[32768]
#define WS_FKEY  38600768ull   // u64[32768]
#define WS_CNT   38862912ull   // int[2]
#define WS_LOSS  38862920ull   // double
#define WS_WL    38866944ull   // ushort[8][512][512]   bf16 lo of W (8MB)

typedef short v8s __attribute__((ext_vector_type(8)));
typedef float v4f __attribute__((ext_vector_type(4)));

__device__ __forceinline__ unsigned short bf16rne(float f) {
  unsigned u = __float_as_uint(f);
  return (unsigned short)((u + 0x7FFFu + ((u >> 16) & 1u)) >> 16);
}
__device__ __forceinline__ float bf16tof(unsigned short h) {
  return __uint_as_float(((unsigned)h) << 16);
}

// async global->LDS DMA, 16B/lane. LDS dest is wave-uniform base; HW writes
// lane l's 16B at base + l*16. Global src is per-lane (we pass base + lane*16).
__device__ __forceinline__ void gl_lds16(const void* g, void* l) {
  __builtin_amdgcn_global_load_lds(
      (const __attribute__((address_space(1))) unsigned int*)g,
      (__attribute__((address_space(3))) unsigned int*)l, 16, 0, 0);
}

__global__ void k_zero(int* __restrict__ hist, unsigned long long* __restrict__ fkey,
                       int* __restrict__ cnt, double* __restrict__ loss,
                       unsigned* __restrict__ maxw) {
  const int i = blockIdx.x * 256 + threadIdx.x;   // grid 161
  if (i < 8192) hist[i] = 0;
  else if (i < 40960) fkey[i - 8192] = ~0ull;
  else if (i == 40960) cnt[0] = 0;
  else if (i == 40961) cnt[1] = 0;
  else if (i == 40962) *loss = 0.0;
  else if (i == 40963) *maxw = 0u;
}

// W -> bf16 hi + lo planes, fragment-linear layout.
// ushort off(j,k) = (k>>5)*262144 + (j>>4)*512 + ((k>>3)&3)*128 + (j&15)*8 + (k&7)
__global__ __launch_bounds__(256) void k_split(const float* __restrict__ W,
                                               unsigned short* __restrict__ Wh,
                                               unsigned short* __restrict__ Wl) {
  const int u = blockIdx.x * 256 + threadIdx.x;   // grid 1024
  const int kc = u >> 15, grp = (u >> 6) & 511, q = (u >> 4) & 3, col = u & 15;
  const int j = grp * 16 + col, k0 = kc * 32 + q * 8;
  const float4 w0 = *(const float4*)(W + (size_t)j * 256 + k0);
  const float4 w1 = *(const float4*)(W + (size_t)j * 256 + k0 + 4);
  const float wv[8] = {w0.x, w0.y, w0.z, w0.w, w1.x, w1.y, w1.z, w1.w};
  unsigned short h[8] __attribute__((aligned(16)));
  unsigned short l[8] __attribute__((aligned(16)));
#pragma unroll
  for (int i = 0; i < 8; ++i) {
    h[i] = bf16rne(wv[i]);
    l[i] = bf16rne(__fsub_rn(wv[i], bf16tof(h[i])));
  }
  *(uint4*)(Wh + (size_t)u * 8) = *(const uint4*)h;
  *(uint4*)(Wl + (size_t)u * 8) = *(const uint4*)l;
}

// z (32,256,32,32) -> Zh/Zl fragment-linear bf16 (n = b*1024 + p).
__global__ __launch_bounds__(256) void k_splitz(const float* __restrict__ z,
    unsigned short* __restrict__ Zh, unsigned short* __restrict__ Zl) {
  const int gt = blockIdx.x * 256 + threadIdx.x;   // grid 1024
  const int kc = gt >> 15;
  const int n  = gt & 32767;
  const int b = n >> 10, p = n & 1023;
  const float* zp = z + (size_t)b * 262144 + (size_t)(kc * 32) * 1024 + p;
  unsigned short hh[32] __attribute__((aligned(16)));
  unsigned short ll[32] __attribute__((aligned(16)));
#pragma unroll
  for (int i = 0; i < 32; ++i) {
    const float v = zp[(size_t)i * 1024];
    const unsigned short h = bf16rne(v);
    hh[i] = h;
    ll[i] = bf16rne(__fsub_rn(v, bf16tof(h)));
  }
  const size_t o = (size_t)kc * 1048576 + (size_t)(n >> 4) * 512 + (size_t)(n & 15) * 8;
#pragma unroll
  for (int q = 0; q < 4; ++q) *(uint4*)(Zh + o + q * 128) = *(const uint4*)(hh + q * 8);
#pragma unroll
  for (int q = 0; q < 4; ++q) *(uint4*)(Zl + o + q * 128) = *(const uint4*)(ll + q * 8);
}

// z -> zT[n][c] f32 (row-major per pixel). Runs AFTER k_main (aliases Zh/Zl).
__global__ __launch_bounds__(256) void k_zt(const float* __restrict__ z,
                                            float* __restrict__ zT) {
  const int gt = blockIdx.x * 256 + threadIdx.x;   // grid 1024
  const int kc = gt >> 15;
  const int n  = gt & 32767;
  const int b = n >> 10, p = n & 1023;
  const float* zp = z + (size_t)b * 262144 + (size_t)(kc * 32) * 1024 + p;
  float v[32] __attribute__((aligned(16)));
#pragma unroll
  for (int i = 0; i < 32; ++i) v[i] = zp[(size_t)i * 1024];
  float* dst = zT + (size_t)n * 256 + kc * 32;
#pragma unroll
  for (int j = 0; j < 8; ++j) *(float4*)(dst + j * 4) = *(const float4*)(v + j * 4);
}

// numpy pairwise sum of squares, n=256 (two 128-blocks, 8 accumulators)
__device__ __forceinline__ float np_sumsq256(const float* __restrict__ base,
                                             const int stride) {
  float h[2];
#pragma unroll
  for (int half = 0; half < 2; ++half) {
    const float* a = base + (size_t)(half * 128) * stride;
    float r[8];
#pragma unroll
    for (int k = 0; k < 8; ++k) { const float v = a[(size_t)k * stride]; r[k] = __fmul_rn(v, v); }
    for (int i = 8; i < 128; i += 8) {
#pragma unroll
      for (int k = 0; k < 8; ++k) {
        const float v = a[(size_t)(i + k) * stride];
        r[k] = __fadd_rn(r[k], __fmul_rn(v, v));
      }
    }
    h[half] = __fadd_rn(
        __fadd_rn(__fadd_rn(r[0], r[1]), __fadd_rn(r[2], r[3])),
        __fadd_rn(__fadd_rn(r[4], r[5]), __fadd_rn(r[6], r[7])));
  }
  return __fadd_rn(h[0], h[1]);
}

__global__ __launch_bounds__(256) void k_sz(const float* __restrict__ z,
                                            float* __restrict__ S) {
  const int n = blockIdx.x * 256 + threadIdx.x;   // grid 128
  S[n] = np_sumsq256(z + (size_t)(n >> 10) * 262144 + (n & 1023), 1024);
}

__global__ __launch_bounds__(256) void k_wsq(const float* __restrict__ W,
                                             float* __restrict__ B,
                                             unsigned* __restrict__ maxw) {
  const int j = blockIdx.x * 256 + threadIdx.x;   // grid 32
  const float b = np_sumsq256(W + (size_t)j * 256, 1);
  B[j] = b;
  atomicMax(maxw, __float_as_uint(b));
}

// stable merge of two sorted-3 lists (values + indices for top-2)
__device__ __forceinline__ void merge5(float& a1, int& ai1, float& a2, int& ai2,
                                       float& a3, float b1, int bi1, float b2,
                                       int bi2, float b3) {
  const bool t1 = (b1 < a1) || (b1 == a1 && bi1 < ai1);
  const float w2v = t1 ? b2 : a2; const int w2i = t1 ? bi2 : ai2;
  const float w3v = t1 ? b3 : a3;
  const float l1v = t1 ? a1 : b1; const int l1i = t1 ? ai1 : bi1;
  const float l2v = t1 ? a2 : b2;
  const float n1v = t1 ? b1 : a1; const int n1i = t1 ? bi1 : ai1;
  const bool t2 = (w2v < l1v) || (w2v == l1v && w2i < l1i);
  a1 = n1v; ai1 = n1i;
  a2 = t2 ? w2v : l1v; ai2 = t2 ? w2i : l1i;
  a3 = t2 ? fminf(w3v, l1v) : fminf(w2v, l2v);
}

// Coarse pass v11: C~ = zh*wh + zl*wh + zh*wl (3 MFMAs, per-acc chain order
// identical to v4-v10 -> bit-identical numerics); window is 2-ulp dominated.
// Round-9 structure (2 barrier domains/CU, 256thr, no spill) + T3/T4 counted
// vmcnt: Bh TRIPLE-buffered (3x8K), DMA issued TWO iterations ahead; each
// iteration ends in raw s_barrier preceded by asm vmcnt(6) -- the 6 newest
// ops (DMA(it+2)x2 + bl(it+1)x4) stay in flight ACROSS the barrier, while
// DMA(it+1) (read next iter, cross-wave) is provably complete (older than
// the allowed 6; bl(it) consumption also drains it). The asm fences pin the
// load issue points (round-10 lesson: unfenced prefetch gets re-sunk).
// A-lo moves to registers (al[8][2], kc statically unrolled) so LDS =
// A-hi 32K + Bh 24K = 56 KiB -> 2 blocks/CU at the 256-reg budget.
#define AH_OFF   0        // 32 KB  A hi: [kc][4 groups][1KB]
#define BH0_OFF  32768    // 8 KB   B hi buf0
#define BH1_OFF  40960    // 8 KB   B hi buf1
#define BH2_OFF  49152    // 8 KB   B hi buf2
#define SC_OFF   0        // merge scratch (reuses AH after loop + barrier)
#define SMEM_SZ  57344
__global__ __launch_bounds__(256, 2) void k_main(
    const unsigned short* __restrict__ Zh, const unsigned short* __restrict__ Zl,
    const unsigned short* __restrict__ Wh, const unsigned short* __restrict__ Wl,
    const float* __restrict__ S, const float* __restrict__ B,
    const unsigned* __restrict__ maxw, int* __restrict__ idxb,
    int* __restrict__ cand, int* __restrict__ full, int* __restrict__ cnt) {
  extern __shared__ __align__(16) char smem[];
  const int t = threadIdx.x;
  const int w = t >> 6, lane = t & 63, col = lane & 15, q = lane >> 4;
  const int phalf = w >> 1, strip = w & 1;
  const int n0 = blockIdx.x << 6;             // grid 512

  float spx[8];
#pragma unroll
  for (int s = 0; s < 8; ++s)
    spx[s] = S[n0 + phalf * 32 + (s >> 2) * 16 + q * 4 + (s & 3)];

  // ---- A hi -> LDS via DMA (once): wave w stages kc = 2w, 2w+1 ----
  {
#pragma unroll
    for (int c = 0; c < 2; ++c) {
      const int kc = w * 2 + c;
      const size_t ab = (size_t)kc * 1048576 + (size_t)(n0 >> 4) * 512 + (size_t)lane * 8;
#pragma unroll
      for (int g = 0; g < 4; ++g)
        gl_lds16(Zh + ab + (size_t)g * 512, smem + AH_OFF + kc * 4096 + g * 1024);
    }
  }
  // ---- A lo -> registers (coalesced 16B/lane, once; kc statically unrolled) ----
  v8s al[8][2];
  {
    const size_t abase = (size_t)(n0 >> 4) * 512 + (size_t)lane * 8;
#pragma unroll
    for (int kc = 0; kc < 8; ++kc)
#pragma unroll
      for (int pt = 0; pt < 2; ++pt)
        al[kc][pt] = *(const v8s*)(Zl + (size_t)kc * 1048576 + abase
                                   + (size_t)(phalf * 2 + pt) * 512);
  }
  // ---- Bh chunks 0,1 -> buf0,buf1 (wave w stages groups 2w, 2w+1) ----
  {
#pragma unroll
    for (int c = 0; c < 2; ++c) {
      const size_t cb = (size_t)c * 262144 + (size_t)(w * 2) * 512 + (size_t)lane * 8;
      char* d = smem + (c ? BH1_OFF : BH0_OFF) + (w * 2) * 1024;
      gl_lds16(Wh + cb,       d);
      gl_lds16(Wh + cb + 512, d + 1024);
    }
  }
  // ---- bl chunk 0 -> blA (this wave's strip: 4 groups) ----
  v8s blA[4], blB[4];
  {
    const unsigned short* p = Wl + (size_t)(strip * 4) * 512 + (size_t)lane * 8;
#pragma unroll
    for (int nt = 0; nt < 4; ++nt) blA[nt] = *(const v8s*)(p + nt * 512);
  }
  asm volatile("s_waitcnt vmcnt(0)" ::: "memory");
  __builtin_amdgcn_s_barrier();
  asm volatile("" ::: "memory");

  float m1[8], m2[8], m3[8]; int i1[8], i2[8];
#pragma unroll
  for (int s = 0; s < 8; ++s) {
    m1[s] = FLT_MAX; m2[s] = FLT_MAX; m3[s] = FLT_MAX;
    i1[s] = 0x7fffffff; i2[s] = 0x7fffffff;
  }

  v4f acc[2][4];
#pragma unroll
  for (int pt = 0; pt < 2; ++pt)
#pragma unroll
    for (int nt = 0; nt < 4; ++nt) acc[pt][nt] = (v4f){0.f, 0.f, 0.f, 0.f};

  char* cur = smem + BH0_OFF;
  char* nxt = smem + BH1_OFF;
  char* nx2 = smem + BH2_OFF;

  for (int it2 = 0; it2 < 64; ++it2) {        // 512 its; counted-vmcnt barriers
#pragma unroll
    for (int kc = 0; kc < 8; ++kc) {
      const int it = it2 * 8 + kc;
      if (it < 510) {                          // DMA Bh(it+2) -> nx2
        const int nc = it + 2;
        const size_t cb = (size_t)(nc & 7) * 262144 + (size_t)(nc >> 3) * 4096
                        + (size_t)(w * 2) * 512 + (size_t)lane * 8;
        char* d = nx2 + (w * 2) * 1024;
        gl_lds16(Wh + cb,       d);
        gl_lds16(Wh + cb + 512, d + 1024);
      }
      {                                        // bl(it+1) -> the buffer not in use
        const int nc2 = (it + 1) & 511;
        const unsigned short* bls = Wl + (size_t)(nc2 & 7) * 262144
                                  + (size_t)(nc2 >> 3) * 4096
                                  + (size_t)(strip * 4) * 512 + (size_t)lane * 8;
        if ((kc & 1) == 0) {
#pragma unroll
          for (int nt = 0; nt < 4; ++nt) blB[nt] = *(const v8s*)(bls + nt * 512);
        } else {
#pragma unroll
          for (int nt = 0; nt < 4; ++nt) blA[nt] = *(const v8s*)(bls + nt * 512);
        }
      }
      v8s ah[2];
#pragma unroll
      for (int pt = 0; pt < 2; ++pt)
        ah[pt] = *(const v8s*)(smem + AH_OFF + kc * 4096
                               + (phalf * 2 + pt) * 1024 + lane * 16);
#pragma unroll
      for (int nt = 0; nt < 4; ++nt) {
        const v8s bh = *(const v8s*)(cur + (strip * 4 + nt) * 1024 + lane * 16);
        const v8s blv = (kc & 1) ? blB[nt] : blA[nt];
#pragma unroll
        for (int pt = 0; pt < 2; ++pt) {
          acc[pt][nt] = __builtin_amdgcn_mfma_f32_16x16x32_bf16(ah[pt], bh, acc[pt][nt], 0, 0, 0);
          acc[pt][nt] = __builtin_amdgcn_mfma_f32_16x16x32_bf16(al[kc][pt], bh, acc[pt][nt], 0, 0, 0);
          acc[pt][nt] = __builtin_amdgcn_mfma_f32_16x16x32_bf16(ah[pt], blv, acc[pt][nt], 0, 0, 0);
        }
      }
      if (kc == 7) {                           // epilogue for this 128-code tile
        const int ct = it >> 3;
#pragma unroll
        for (int nt = 0; nt < 4; ++nt) {
          const int code = ct * 128 + strip * 64 + nt * 16 + col;
          const float bb = B[code];
#pragma unroll
          for (int pt = 0; pt < 2; ++pt) {
            const v4f a = acc[pt][nt];
#pragma unroll
            for (int r = 0; r < 4; ++r) {
              const int s = pt * 4 + r;
              const float d = __fsub_rn(__fadd_rn(spx[s], bb), __fmul_rn(2.f, a[r]));
              const bool c1 = (d < m1[s]);
              const bool c2 = (d < m2[s]);
              const bool c3 = (d < m3[s]);
              m3[s] = c2 ? m2[s] : (c3 ? d : m3[s]);
              m2[s] = c1 ? m1[s] : (c2 ? d : m2[s]);
              i2[s] = c1 ? i1[s] : (c2 ? code : i2[s]);
              m1[s] = c1 ? d : m1[s];
              i1[s] = c1 ? code : i1[s];
            }
          }
#pragma unroll
          for (int pt = 0; pt < 2; ++pt) acc[pt][nt] = (v4f){0.f, 0.f, 0.f, 0.f};
        }
      }
      if (it < 511) {
        // counted wait: allow DMA(it+2)x2 + bl(it+1)x4 to span the barrier;
        // everything older (incl. DMA(it+1), read next iter) is complete.
        asm volatile("s_waitcnt vmcnt(6)" ::: "memory");
        __builtin_amdgcn_s_barrier();
        asm volatile("" ::: "memory");
      }
      char* tmp = cur; cur = nxt; nxt = nx2; nx2 = tmp;
    }
  }

  // in-wave merge across the 16 col-lanes
#pragma unroll
  for (int s = 0; s < 8; ++s) {
    for (int msk = 1; msk < 16; msk <<= 1) {
      const float b1 = __shfl_xor(m1[s], msk, 16);
      const int  bi1 = __shfl_xor(i1[s], msk, 16);
      const float b2 = __shfl_xor(m2[s], msk, 16);
      const int  bi2 = __shfl_xor(i2[s], msk, 16);
      const float b3 = __shfl_xor(m3[s], msk, 16);
      merge5(m1[s], i1[s], m2[s], i2[s], m3[s], b1, bi1, b2, bi2, b3);
    }
  }
  __syncthreads();   // all waves done with LDS -> safe to reuse as scratch
  float* sc = (float*)(smem + SC_OFF);        // [px][strip][5]
  if (col == 0) {
#pragma unroll
    for (int s = 0; s < 8; ++s) {
      const int px = phalf * 32 + (s >> 2) * 16 + q * 4 + (s & 3);
      const int base = (px * 2 + strip) * 5;
      sc[base]     = m1[s];
      sc[base + 1] = __int_as_float(i1[s]);
      sc[base + 2] = m2[s];
      sc[base + 3] = __int_as_float(i2[s]);
      sc[base + 4] = m3[s];
    }
  }
  __syncthreads();
  if (t < 64) {
    const int base0 = t * 10;
    float A1 = sc[base0], A2 = sc[base0 + 2], A3 = sc[base0 + 4];
    int AI1 = __float_as_int(sc[base0 + 1]), AI2 = __float_as_int(sc[base0 + 3]);
    {
      const int base = base0 + 5;
      merge5(A1, AI1, A2, AI2, A3, sc[base], __float_as_int(sc[base + 1]),
             sc[base + 2], __float_as_int(sc[base + 3]), sc[base + 4]);
    }
    const int n = n0 + t;
    idxb[n] = AI1;
    // window: 2*(2^-16*||z||*max||w|| + slack) + 2 ulp(m1)
    const float nw = sqrtf(S[n]) * sqrtf(__uint_as_float(*maxw));
    const float win = 2.0f * (1.52587890625e-05f * nw + 1e-6f)
                    + 2.0f * ldexpf(1.0f, ilogbf(fmaxf(A1, 1e-30f)) - 23);
    if (A2 <= A1 + win) {
      if (A3 <= A1 + win) {
        const int p = atomicAdd(&cnt[1], 1);
        full[p] = n;
      } else {
        const int p = atomicAdd(&cnt[0], 1);
        cand[3 * p] = n; cand[3 * p + 1] = AI1; cand[3 * p + 2] = AI2;
      }
    }
  }
}

// exact np-chain re-eval of the two candidates (z rows via zT, sequential)
__global__ __launch_bounds__(256) void k_cand(const float* __restrict__ zT,
    const float* __restrict__ W, const float* __restrict__ S,
    const float* __restrict__ B, const int* __restrict__ cand,
    const int* __restrict__ cnt, int* __restrict__ idxb) {
  const int e = blockIdx.x * 256 + threadIdx.x;   // grid 128
  if (e >= cnt[0]) return;
  const int n = cand[3 * e], ca = cand[3 * e + 1], cb = cand[3 * e + 2];
  const float* zp = zT + (size_t)n * 256;
  const float* wa = W + (size_t)ca * 256;
  const float* wb = W + (size_t)cb * 256;
  float a1 = 0.f, a2 = 0.f;
  for (int c = 0; c < 256; ++c) {
    const float zv = zp[c];
    a1 = __builtin_fmaf(zv, wa[c], a1);
    a2 = __builtin_fmaf(zv, wb[c], a2);
  }
  const float d1 = __fsub_rn(__fadd_rn(S[n], B[ca]), __fmul_rn(2.f, a1));
  const float d2 = __fsub_rn(__fadd_rn(S[n], B[cb]), __fmul_rn(2.f, a2));
  idxb[n] = (d1 < d2) ? ca : ((d2 < d1) ? cb : min(ca, cb));
}

// Exact full argmin. Unit = (32-px group, 256-code tile) -> units = nG*32.
__global__ __launch_bounds__(256) void k_full(const float* __restrict__ zT,
    const float* __restrict__ W, const float* __restrict__ S,
    const float* __restrict__ B, const int* __restrict__ full,
    const int* __restrict__ cnt, unsigned long long* __restrict__ fkey) {
  extern __shared__ __align__(16) char fsm[];
  float* zsf = (float*)fsm;                    // [256][32] (swizzled quads)
  float* wt  = (float*)(fsm + 32768);          // [32][257]
  float* mv  = (float*)(fsm + 32768 + 32896);  // [32][33]
  int*   mi  = (int*)(fsm + 32768 + 32896 + 4224);
  const int t = threadIdx.x;
  const int pg = t & 7, cg = t >> 3;
  const int fN = min(cnt[1], 32768);
  const int units = ((fN + 31) >> 5) << 5;
  for (int e = blockIdx.x; e < units; e += 2048) {
    const int g = e >> 5, tt = e & 31;
    const int c0 = tt << 8;
    __syncthreads();                           // LDS reuse guard
    {                                          // stage z from zT (coalesced)
      const int px = t >> 3, c8 = t & 7;
      const int f = (g << 5) + px;
      const int n = (f < fN) ? full[f] : full[0];
      const float4* src = (const float4*)(zT + (size_t)n * 256 + c8 * 32);
      const int colq = (((px >> 2) ^ c8) << 2) + (px & 3);
#pragma unroll
      for (int j = 0; j < 8; ++j) {
        const float4 v = src[j];
        const int c = c8 * 32 + j * 4;
        zsf[(c    ) * 32 + colq] = v.x;
        zsf[(c + 1) * 32 + colq] = v.y;
        zsf[(c + 2) * 32 + colq] = v.z;
        zsf[(c + 3) * 32 + colq] = v.w;
      }
    }
    float s4[4];
#pragma unroll
    for (int i = 0; i < 4; ++i) {
      const int f = (g << 5) + (pg << 2) + i;
      s4[i] = (f < fN) ? S[full[f]] : 0.f;
    }
    float bm[4]; int bj[4];
#pragma unroll
    for (int i = 0; i < 4; ++i) { bm[i] = FLT_MAX; bj[i] = 0x7fffffff; }
    float acc[4][8];
#pragma unroll
    for (int i = 0; i < 4; ++i)
#pragma unroll
      for (int u = 0; u < 8; ++u) acc[i][u] = 0.f;
    for (int kc = 0; kc < 8; ++kc) {
      const int kb = kc << 5;
      __syncthreads();
#pragma unroll
      for (int p = 0; p < 8; ++p) {          // W chunk, transposed store
        const int jl = (t >> 3) + (p << 5);
        const float4 wv4 =
            *(const float4*)&W[(size_t)(c0 + jl) * 256 + kb + ((t & 7) << 2)];
        const int k0 = (t & 7) << 2;
        wt[(k0    ) * 257 + jl] = wv4.x;
        wt[(k0 + 1) * 257 + jl] = wv4.y;
        wt[(k0 + 2) * 257 + jl] = wv4.z;
        wt[(k0 + 3) * 257 + jl] = wv4.w;
      }
      __syncthreads();
      const int zq = ((pg ^ kc) & 7) << 2;
      for (int k = 0; k < 32; ++k) {
        const float4 z4 = *(const float4*)&zsf[(kb + k) * 32 + zq];
        const float4 wA = *(const float4*)&wt[k * 257 + (cg << 3)];
        const float4 wB = *(const float4*)&wt[k * 257 + (cg << 3) + 4];
        const float zv[4] = {z4.x, z4.y, z4.z, z4.w};
        const float wv[8] = {wA.x, wA.y, wA.z, wA.w, wB.x, wB.y, wB.z, wB.w};
#pragma unroll
        for (int i = 0; i < 4; ++i)
#pragma unroll
          for (int u = 0; u < 8; ++u)
            acc[i][u] = __builtin_fmaf(zv[i], wv[u], acc[i][u]);
      }
    }
#pragma unroll
    for (int u = 0; u < 8; ++u) {              // tile epilogue
      const int code = c0 + (cg << 3) + u;
      const float bb = B[code];
#pragma unroll
      for (int i = 0; i < 4; ++i) {
        const float d = __fsub_rn(__fadd_rn(s4[i], bb), __fmul_rn(2.f, acc[i][u]));
        if (d < bm[i]) { bm[i] = d; bj[i] = code; }
      }
    }
    __syncthreads();                           // merge across cg
#pragma unroll
    for (int i = 0; i < 4; ++i) {
      const int px = (pg << 2) + i;
      mv[px * 33 + cg] = bm[i];
      mi[px * 33 + cg] = bj[i];
    }
    __syncthreads();
    if (t < 32) {
      float m = mv[t * 33]; int j = mi[t * 33];
      for (int c = 1; c < 32; ++c) {
        const float v = mv[t * 33 + c]; const int vi = mi[t * 33 + c];
        if (v < m || (v == m && vi < j)) { m = v; j = vi; }
      }
      const int f = (g << 5) + t;
      if (f < fN) {
        const unsigned long long key =
            (((unsigned long long)__float_as_uint(m)) << 13) | (unsigned)j;
        atomicMin(&fkey[f], key);
      }
    }
  }
}

__global__ __launch_bounds__(256) void k_fullfin(const int* __restrict__ full,
    const int* __restrict__ cnt, const unsigned long long* __restrict__ fkey,
    int* __restrict__ idxb) {
  const int f = blockIdx.x * 256 + threadIdx.x;   // grid 128
  if (f < cnt[1]) idxb[full[f]] = (int)(fkey[f] & 8191ull);
}

// z_q gather (STE rounding) + loss + histogram + index output
__global__ __launch_bounds__(256) void k_zq(const float* __restrict__ z,
    const float* __restrict__ W, const int* __restrict__ idxb,
    float* __restrict__ out, double* __restrict__ loss, int* __restrict__ hist) {
  __shared__ float red[256];
  const int t = threadIdx.x;
  const int tx = t & 63, ty = t >> 6;
  const int n0 = blockIdx.x << 6;            // grid 512
  const int n = n0 + tx;
  const int b = n >> 10;
  const int p = n & 1023;
  const int myidx = idxb[n];
  const float* wrow = W + (size_t)myidx * 256;
  float lsum = 0.f;
#pragma unroll 4
  for (int cc = 0; cc < 64; ++cc) {
    const int c = ty * 64 + cc;
    const float qv = wrow[c];
    const size_t off = (size_t)b * 262144 + (size_t)c * 1024 + p;
    const float zv = z[off];
    const float d = __fsub_rn(qv, zv);
    lsum = __builtin_fmaf(d, d, lsum);
    out[off] = __fadd_rn(zv, d);
  }
  red[t] = lsum;
  __syncthreads();
  for (int o = 128; o > 0; o >>= 1) {
    if (t < o) red[t] += red[t + o];
    __syncthreads();
  }
  if (t == 0) atomicAdd(loss, (double)red[0]);
  if (ty == 0) atomicAdd(&hist[myidx], 1);
  if (ty == 1) out[OUT_IDX + n] = (float)myidx;
}

__global__ void k_final(const int* __restrict__ hist,
                        const double* __restrict__ loss,
                        float* __restrict__ out) {
  __shared__ double sh[256];
  const int t = threadIdx.x;
  double s = 0.0;
  for (int j = t; j < 8192; j += 256) {
    const double e = (double)hist[j] / 32768.0;
    s += e * log(e + 1e-10);
  }
  sh[t] = s;
  __syncthreads();
  for (int off = 128; off > 0; off >>= 1) {
    if (t < off) sh[t] += sh[t + off];
    __syncthreads();
  }
  if (t == 0) {
    out[OUT_PERP] = (float)exp(-sh[0]);
    out[OUT_LOSS] = (float)(1.25 * (*loss) / 8388608.0);
  }
}

extern "C" void kernel_launch(void* const* d_in, const int* in_sizes, int n_in,
                              void* d_out, int out_size, void* d_ws, size_t ws_size,
                              hipStream_t stream) {
  const float* z = (const float*)d_in[0];
  const float* W = (const float*)d_in[1];
  float* out = (float*)d_out;
  char* ws = (char*)d_ws;
  unsigned short* Zh = (unsigned short*)(ws + WS_ZH);
  unsigned short* Zl = (unsigned short*)(ws + WS_ZL);
  unsigned short* Wh = (unsigned short*)(ws + WS_WH);
  unsigned short* Wl = (unsigned short*)(ws + WS_WL);
  float*  zT   = (float*)(ws + WS_ZT);   // aliases Zh+Zl (dead after k_main)
  float*  S    = (float*)(ws + WS_S);
  float*  B    = (float*)(ws + WS_B);
  unsigned* maxw = (unsigned*)(ws + WS_MAXW);
  int*    idxb = (int*)(ws + WS_IDX);
  int*    hist = (int*)(ws + WS_HIST);
  int*    cand = (int*)(ws + WS_CAND);
  int*    full = (int*)(ws + WS_FULL);
  unsigned long long* fkey = (unsigned long long*)(ws + WS_FKEY);
  int*    cnt  = (int*)(ws + WS_CNT);
  double* loss = (double*)(ws + WS_LOSS);

  hipLaunchKernelGGL(k_zero,    dim3(161),  dim3(256), 0, stream, hist, fkey, cnt, loss, maxw);
  hipLaunchKernelGGL(k_split,   dim3(1024), dim3(256), 0, stream, W, Wh, Wl);
  hipLaunchKernelGGL(k_splitz,  dim3(1024), dim3(256), 0, stream, z, Zh, Zl);
  hipLaunchKernelGGL(k_sz,      dim3(128),  dim3(256), 0, stream, z, S);
  hipLaunchKernelGGL(k_wsq,     dim3(32),   dim3(256), 0, stream, W, B, maxw);
  hipLaunchKernelGGL(k_main,    dim3(512),  dim3(256), SMEM_SZ, stream,
                     Zh, Zl, Wh, Wl, S, B, maxw, idxb, cand, full, cnt);
  hipLaunchKernelGGL(k_zt,      dim3(1024), dim3(256), 0, stream, z, zT);
  hipLaunchKernelGGL(k_cand,    dim3(128),  dim3(256), 0, stream, zT, W, S, B, cand, cnt, idxb);
  hipLaunchKernelGGL(k_full,    dim3(2048), dim3(256), 74112, stream, zT, W, S, B, full, cnt, fkey);
  hipLaunchKernelGGL(k_fullfin, dim3(128),  dim3(256), 0, stream, full, cnt, fkey, idxb);
  hipLaunchKernelGGL(k_zq,      dim3(512),  dim3(256), 0, stream, z, W, idxb, out, loss, hist);
  hipLaunchKernelGGL(k_final,   dim3(1),    dim3(256), 0, stream, hist, loss, out);
}